// Round 13
// baseline (48.542 us; speedup 1.0000x reference)
//
#include <hip/hip_runtime.h>
#include <hip/hip_bf16.h>
#include <cstdint>

// Problem constants (ConceptBoxModel): B=256, L=512, N=64, D=32, C=100
constexpr int Bb = 256, Ll = 512, Nn = 64, Dd = 32, Cc = 100;
constexpr float EPS = 1e-6f;

typedef __attribute__((ext_vector_type(8))) short short8;   // 8 bf16
typedef __attribute__((ext_vector_type(4))) short short4v;  // 4 bf16
typedef __attribute__((ext_vector_type(4))) float f32x4;    // MFMA C/D frag

__device__ __forceinline__ unsigned short f2bf(float f) {
  union { float f; uint32_t u; } v; v.f = f;
  uint32_t r = v.u + 0x7FFFu + ((v.u >> 16) & 1u);   // RNE
  return (unsigned short)(r >> 16);
}

// ---------------------------------------------------------------------------
// Kernel A v9 (MFMA, intra-block split-K): 256 blocks x 512 thr (8 waves).
// kg=0/1 each accumulate 4 of 8 K-chunks in private LDS tiles; LDS reduce;
// kg=0 epilogue.  2 waves/SIMD for latency hiding.
// ---------------------------------------------------------------------------
__global__ __launch_bounds__(512) void kA(
    const float* __restrict__ h,    // [256][512]
    const float* __restrict__ Wc,   // [64][512][32]
    const float* __restrict__ bc,   // [64][32]
    const float* __restrict__ Wo,
    const float* __restrict__ bo,
    const float* __restrict__ Wp,   // [64][64]
    const float* __restrict__ bp,   // [64]
    const float* __restrict__ b1,   // [100]
    const float* __restrict__ b2,   // [100]
    float* __restrict__ xm_ws,      // [256][64][32]
    float* __restrict__ dl_ws,      // [256][64][32]
    unsigned short* __restrict__ abuf,  // [256][8192] bf16 (first half)
    float* __restrict__ out_ph,     // [256][64]
    float* __restrict__ out_y)      // [256][100] (init only)
{
  const int n  = blockIdx.x;
  const int bt = blockIdx.y * 64;
  const int t  = threadIdx.x;     // 0..511
  const int kg = t >> 8;          // K-group 0/1
  const int tl = t & 255;
  const int w  = tl >> 6, l = tl & 63;
  const int lr = l & 15, lg = l >> 4;

  // init y with biases (one block per output row)
  {
    const int bid = blockIdx.x + Nn * blockIdx.y;   // 0..255
    if (t < Cc) out_y[bid * Cc + t] = b1[t] + b2[t];
  }

  __shared__ union USmA {
    struct {
      unsigned short hb[2][64][72];    // [kg][row][k] bf16, 144B rows
      unsigned short wbT[2][64][72];   // [kg][col][k]
    } s;
    float red[16][264];                // cross-group reduce (16.9 KB)
  } u;

  f32x4 acc[4] = {};   // nf=0,1 -> xm cols ; nf=2,3 -> dl cols

  const int hr = tl >> 2,       hc  = (tl & 3) * 16;   // h staging
  const int wk = (tl >> 3) * 2, wcq = (tl & 7) * 4;    // W staging
  const float* hsrc  = h  + (bt + hr) * Ll + hc;
  const float* wcsrc = Wc + n * (Ll * Dd) + wk * Dd + wcq;
  const float* wosrc = Wo + n * (Ll * Dd) + wk * Dd + wcq;

  float4 hp0, hp1, hp2, hp3, c0, c1, o0, o1;
  auto fetch = [&](int k0) {
    const float* hs = hsrc + k0;
    hp0 = *(const float4*)(hs);
    hp1 = *(const float4*)(hs + 4);
    hp2 = *(const float4*)(hs + 8);
    hp3 = *(const float4*)(hs + 12);
    const float* ws = wcsrc + k0 * Dd;
    c0 = *(const float4*)(ws);
    c1 = *(const float4*)(ws + Dd);
    const float* os = wosrc + k0 * Dd;
    o0 = *(const float4*)(os);
    o1 = *(const float4*)(os + Dd);
  };

  fetch(kg * 256);
  for (int ch = 0; ch < 4; ch++) {
    __syncthreads();
    {
      // pack 16 bf16 in regs, 2 x b128 stores
      short8 s0, s1;
      s0[0] = (short)f2bf(hp0.x); s0[1] = (short)f2bf(hp0.y);
      s0[2] = (short)f2bf(hp0.z); s0[3] = (short)f2bf(hp0.w);
      s0[4] = (short)f2bf(hp1.x); s0[5] = (short)f2bf(hp1.y);
      s0[6] = (short)f2bf(hp1.z); s0[7] = (short)f2bf(hp1.w);
      s1[0] = (short)f2bf(hp2.x); s1[1] = (short)f2bf(hp2.y);
      s1[2] = (short)f2bf(hp2.z); s1[3] = (short)f2bf(hp2.w);
      s1[4] = (short)f2bf(hp3.x); s1[5] = (short)f2bf(hp3.y);
      s1[6] = (short)f2bf(hp3.z); s1[7] = (short)f2bf(hp3.w);
      *(short8*)&u.s.hb[kg][hr][hc]     = s0;
      *(short8*)&u.s.hb[kg][hr][hc + 8] = s1;
    }
    {
      const float* c0p = &c0.x; const float* c1p = &c1.x;
      const float* o0p = &o0.x; const float* o1p = &o1.x;
      #pragma unroll
      for (int i = 0; i < 4; i++) {
        unsigned int pc = (unsigned int)f2bf(c0p[i]) |
                          ((unsigned int)f2bf(c1p[i]) << 16);
        *(unsigned int*)&u.s.wbT[kg][wcq + i][wk] = pc;
        unsigned int po = (unsigned int)f2bf(o0p[i]) |
                          ((unsigned int)f2bf(o1p[i]) << 16);
        *(unsigned int*)&u.s.wbT[kg][32 + wcq + i][wk] = po;
      }
    }
    __syncthreads();
    if (ch < 3) fetch(kg * 256 + (ch + 1) * 64);
    const int arow = w * 16 + lr;
    #pragma unroll
    for (int ks = 0; ks < 2; ks++) {
      const int ko = ks * 32 + lg * 8;
      const short8 av = *(const short8*)&u.s.hb[kg][arow][ko];
      #pragma unroll
      for (int nf = 0; nf < 4; nf++) {
        const short8 bv = *(const short8*)&u.s.wbT[kg][nf * 16 + lr][ko];
        acc[nf] = __builtin_amdgcn_mfma_f32_16x16x32_bf16(av, bv, acc[nf],
                                                          0, 0, 0);
      }
    }
  }

  // ---- cross-group reduce ----
  __syncthreads();
  if (kg == 1) {
    #pragma unroll
    for (int nf = 0; nf < 4; nf++)
      #pragma unroll
      for (int q = 0; q < 4; q++) u.red[nf * 4 + q][tl] = acc[nf][q];
  }
  __syncthreads();
  if (kg == 0) {
    const float bc0 = bc[n * Dd + lr],      bc1 = bc[n * Dd + 16 + lr];
    const float bo0 = bo[n * Dd + lr],      bo1 = bo[n * Dd + 16 + lr];
    const float wp0 = Wp[n * 64 + lr],      wp1 = Wp[n * 64 + 16 + lr];
    const float wp2 = Wp[n * 64 + 32 + lr], wp3 = Wp[n * 64 + 48 + lr];
    const float bpv = bp[n];

    #pragma unroll
    for (int q = 0; q < 4; q++) {
      const int b = bt + w * 16 + lg * 4 + q;
      const float xm0  = acc[0][q] + u.red[q][tl]      + bc0;
      const float xm1  = acc[1][q] + u.red[4 + q][tl]  + bc1;
      const float pre0 = acc[2][q] + u.red[8 + q][tl]  + bo0;
      const float pre1 = acc[3][q] + u.red[12 + q][tl] + bo1;
      // stable softplus = max(x,0) + log1p(exp(-|x|))
      const float dl0 = fmaxf(pre0, 0.f) + log1pf(expf(-fabsf(pre0)));
      const float dl1 = fmaxf(pre1, 0.f) + log1pf(expf(-fabsf(pre1)));
      float* xp = xm_ws + b * 2048 + n * Dd;
      float* dp = dl_ws + b * 2048 + n * Dd;
      xp[lr] = xm0;  xp[16 + lr] = xm1;
      dp[lr] = dl0;  dp[16 + lr] = dl1;
      float pp = xm0 * wp0 + xm1 * wp1 + dl0 * wp2 + dl1 * wp3;
      pp += __shfl_xor(pp, 1);
      pp += __shfl_xor(pp, 2);
      pp += __shfl_xor(pp, 4);
      pp += __shfl_xor(pp, 8);
      // after xor-butterfly all 16 lanes hold the sum
      const float ph = 1.f / (1.f + expf(-(pp + bpv)));
      unsigned short* ab = abuf + b * 8192 + n * 64;
      ab[lr]      = f2bf(xm0 * ph);
      ab[16 + lr] = f2bf(xm1 * ph);
      ab[32 + lr] = f2bf(dl0 * ph);
      ab[48 + lr] = f2bf(dl1 * ph);
      if (lr == 0) out_ph[b * 64 + n] = ph;
    }
  }
}

// ---------------------------------------------------------------------------
// Kernel B v5: pairwise intersection volumes.  One block (512 thr) per b.
// j-box in registers; i broadcast from LDS.  V -> d_out f32 + abuf bf16.
// ---------------------------------------------------------------------------
__global__ __launch_bounds__(512) void kB(
    const float* __restrict__ xm_ws,
    const float* __restrict__ dl_ws,
    float* __restrict__ out_V,              // [256][64][64]
    unsigned short* __restrict__ abuf)      // [256][8192] bf16 (second half)
{
  const int b = blockIdx.x, t = threadIdx.x;
  __shared__ float lo[64][36];
  __shared__ float hi[64][36];

  {
    const int n = t >> 3, dd = (t & 7) * 4;
    float4 x = *(const float4*)(xm_ws + b * 2048 + n * Dd + dd);
    float4 g = *(const float4*)(dl_ws + b * 2048 + n * Dd + dd);
    lo[n][dd + 0] = x.x - g.x;  hi[n][dd + 0] = x.x + g.x;
    lo[n][dd + 1] = x.y - g.y;  hi[n][dd + 1] = x.y + g.y;
    lo[n][dd + 2] = x.z - g.z;  hi[n][dd + 2] = x.z + g.z;
    lo[n][dd + 3] = x.w - g.w;  hi[n][dd + 3] = x.w + g.w;
  }
  __syncthreads();

  const int j  = t & 63;
  const int wv = t >> 6;     // wave id: i-range wv*8 .. wv*8+7

  float4 lj[8], hj[8];
  #pragma unroll
  for (int q = 0; q < 8; q++) {
    lj[q] = *(const float4*)&lo[j][q * 4];
    hj[q] = *(const float4*)&hi[j][q * 4];
  }
  float pr = 1.f;
  #pragma unroll
  for (int q = 0; q < 8; q++) {
    pr *= ((hj[q].x - lj[q].x) * 0.5f + EPS);
    pr *= ((hj[q].y - lj[q].y) * 0.5f + EPS);
    pr *= ((hj[q].z - lj[q].z) * 0.5f + EPS);
    pr *= ((hj[q].w - lj[q].w) * 0.5f + EPS);
  }
  const float rv = 1.f / pr;

  #pragma unroll 1
  for (int it = 0; it < 8; it++) {
    const int i = wv * 8 + it;
    float prod = 1.f;
    #pragma unroll
    for (int q = 0; q < 8; q++) {
      const float4 hv = *(const float4*)&hi[i][q * 4];   // broadcast
      const float4 lv = *(const float4*)&lo[i][q * 4];   // broadcast
      float v0 = fmaxf((fminf(hv.x, hj[q].x) - fmaxf(lv.x, lj[q].x)) * 0.5f + EPS, EPS);
      float v1 = fmaxf((fminf(hv.y, hj[q].y) - fmaxf(lv.y, lj[q].y)) * 0.5f + EPS, EPS);
      float v2 = fmaxf((fminf(hv.z, hj[q].z) - fmaxf(lv.z, lj[q].z)) * 0.5f + EPS, EPS);
      float v3 = fmaxf((fminf(hv.w, hj[q].w) - fmaxf(lv.w, lj[q].w)) * 0.5f + EPS, EPS);
      prod *= v0 * v1 * v2 * v3;
    }
    const float V = prod * rv;
    out_V[b * 4096 + i * 64 + j] = V;
    abuf[b * 8192 + 4096 + i * 64 + j] = f2bf(V);
  }
}

// ---------------------------------------------------------------------------
// Kernel C v9 (MFMA split-K, intra-block split): 256 blocks x 512 thr.
// kg handles one 64-k chunk of the 128-k slice: single stage -> sync -> 14
// MFMA (no serial chunk dependency); LDS reduce; kg=0 atomics.
// ---------------------------------------------------------------------------
__global__ __launch_bounds__(512) void kC(
    const unsigned short* __restrict__ abuf,   // [256][8192] bf16
    const float* __restrict__ W1,      // [4096][100]
    const float* __restrict__ W2,      // [4096][100]
    float* __restrict__ out_y)         // [256][100] accumulate
{
  const int Mg = blockIdx.x;           // 4 row-groups of 64
  const int s  = blockIdx.y;           // 64 K-slices of 128
  const bool isV = (s >= 32);
  const int m0 = (s & 31) * 128;       // offset within half
  const float* __restrict__ W = isV ? W2 : W1;
  const int b0 = Mg * 64;

  const int t  = threadIdx.x;          // 0..511
  const int kg = t >> 8;               // chunk 0/1 (64 k each)
  const int tl = t & 255;
  const int w  = tl >> 6, l = tl & 63;
  const int lr = l & 15, lg = l >> 4;

  __shared__ union USmC {
    struct {
      unsigned short Ab[2][64][76];    // [kg][row][k] bf16, 152B rows
      unsigned short Wb[2][112][76];   // [kg][col][k]
    } s;
    float red[28][264];                // cross-group reduce (29.6 KB)
  } u;

  f32x4 acc[7] = {};

  // A staging: ar = row (64), ak = 16-k run base (2x16B per thread)
  const int ar = tl >> 2, ak = (tl & 3) * 16;
  const unsigned short* asrc =
      abuf + (b0 + ar) * 8192 + (isV ? 4096 : 0) + m0 + kg * 64 + ak;
  // W staging: wc = col (128 lanes), half = 32-k half
  const int wc = tl & 127, half = tl >> 7;

  const short8 a0 = *(const short8*)(asrc);
  const short8 a1 = *(const short8*)(asrc + 8);
  float wv[32];
  if (wc < Cc) {
    const float* wp = W + (m0 + kg * 64 + half * 32) * Cc + wc;
    #pragma unroll
    for (int i = 0; i < 32; i++) wv[i] = wp[i * Cc];
  }

  // ---- stage ----
  *(short8*)&u.s.Ab[kg][ar][ak]     = a0;
  *(short8*)&u.s.Ab[kg][ar][ak + 8] = a1;
  if (wc < 112) {
    #pragma unroll
    for (int q8 = 0; q8 < 8; q8++) {
      short4v pk;
      if (wc < Cc) {
        pk[0] = (short)f2bf(wv[q8 * 4 + 0]);
        pk[1] = (short)f2bf(wv[q8 * 4 + 1]);
        pk[2] = (short)f2bf(wv[q8 * 4 + 2]);
        pk[3] = (short)f2bf(wv[q8 * 4 + 3]);
      } else {
        pk[0] = 0; pk[1] = 0; pk[2] = 0; pk[3] = 0;
      }
      *(short4v*)&u.s.Wb[kg][wc][half * 32 + q8 * 4] = pk;
    }
  }
  __syncthreads();

  // ---- 14 MFMA ----
  #pragma unroll
  for (int ks = 0; ks < 2; ks++) {
    const int ko = ks * 32 + lg * 8;
    const short8 av = *(const short8*)&u.s.Ab[kg][w * 16 + lr][ko];
    #pragma unroll
    for (int nf = 0; nf < 7; nf++) {
      const short8 bv = *(const short8*)&u.s.Wb[kg][nf * 16 + lr][ko];
      acc[nf] = __builtin_amdgcn_mfma_f32_16x16x32_bf16(av, bv, acc[nf],
                                                        0, 0, 0);
    }
  }

  // ---- cross-group reduce, then atomics from kg=0 ----
  __syncthreads();
  if (kg == 1) {
    #pragma unroll
    for (int nf = 0; nf < 7; nf++)
      #pragma unroll
      for (int q = 0; q < 4; q++) u.red[nf * 4 + q][tl] = acc[nf][q];
  }
  __syncthreads();
  if (kg == 0) {
    #pragma unroll
    for (int nf = 0; nf < 7; nf++) {
      const int col = nf * 16 + lr;
      if (col < Cc) {
        #pragma unroll
        for (int q = 0; q < 4; q++) {
          const int row = b0 + w * 16 + lg * 4 + q;
          atomicAdd(out_y + row * Cc + col, acc[nf][q] + u.red[nf * 4 + q][tl]);
        }
      }
    }
  }
}

// ---------------------------------------------------------------------------
extern "C" void kernel_launch(void* const* d_in, const int* in_sizes, int n_in,
                              void* d_out, int out_size, void* d_ws, size_t ws_size,
                              hipStream_t stream) {
  const float* h  = (const float*)d_in[0];
  const float* Wc = (const float*)d_in[1];
  const float* bc = (const float*)d_in[2];
  const float* Wo = (const float*)d_in[3];
  const float* bo = (const float*)d_in[4];
  const float* Wp = (const float*)d_in[5];
  const float* bp = (const float*)d_in[6];
  const float* W1 = (const float*)d_in[7];
  const float* b1 = (const float*)d_in[8];
  const float* W2 = (const float*)d_in[9];
  const float* b2 = (const float*)d_in[10];

  float* out    = (float*)d_out;
  float* out_y  = out;                         // [256][100]
  float* out_ph = out + Bb * Cc;               // [256][64]
  float* out_V  = out + Bb * Cc + Bb * Nn;     // [256][64][64]

  float* xm = (float*)d_ws;                        // 524288 f32 (2 MB)
  float* dl = xm + Bb * Nn * Dd;                   // 524288 f32 (2 MB)
  unsigned short* abuf = (unsigned short*)(dl + Bb * Nn * Dd);  // 4 MB bf16

  kA<<<dim3(Nn, Bb / 64), 512, 0, stream>>>(h, Wc, bc, Wo, bo, Wp, bp,
                                            b1, b2, xm, dl, abuf, out_ph, out_y);
  kB<<<Bb, 512, 0, stream>>>(xm, dl, out_V, abuf);
  kC<<<dim3(4, 64), 512, 0, stream>>>(abuf, W1, W2, out_y);
}